// Round 18
// baseline (87.108 us; speedup 1.0000x reference)
//
#include <hip/hip_runtime.h>
#include <hip/hip_bf16.h>

// Problem: B=128, M=256, T=512, N=512
// D[k][n] = sum_t We2T[k][t]*X[t][n] per b; e[b,n] = sum_k tanh(D+g[b,k])*v[k];
// attn = softmax_n(e).  kblk=2 partials summed in softmax.
// R18: pure-TLP design.  NO LDS staging, NO barriers, NO manual waitcnt.
// Each wave self-paces: A-frags b128 from L2-hot Af; B-frags gathered
// directly from global X (4 waves/block read IDENTICAL X addrs -> L1).
// 12 independent waves/CU co-schedule MFMA+VALU+VMEM (m114 mechanism).

typedef _Float16 half8 __attribute__((ext_vector_type(8)));
typedef _Float16 half2v __attribute__((ext_vector_type(2)));
typedef float floatx4 __attribute__((ext_vector_type(4)));

__device__ __forceinline__ float fast_tanh(float x) {
    float cx = fminf(15.0f, fmaxf(-15.0f, x));
    float e = __expf(2.0f * cx);
    return (e - 1.0f) * __fdividef(1.0f, e + 1.0f);
}

// ---------------- K0: Af slabs (A = We2^T f16, frag-linear) ----------------
// slab ts (32 t), chunk kg (0..31), lane l holds
// A[k=kg*16+(l&15)][t=ts*32+(l>>4)*8+j], j=0..7.  Elem ofs: ts*16384+kg*512+l*8.
__global__ __launch_bounds__(256) void k_prep_a(const float* __restrict__ We2,
                                                _Float16* __restrict__ Af) {
    __shared__ float w2[32][512];
    const int ts = blockIdx.x;
    for (int idx = threadIdx.x; idx < 32 * 512; idx += 256) {
        int tl = idx >> 9, k = idx & 511;
        w2[tl][k] = We2[(ts * 32 + tl) * 512 + k];
    }
    __syncthreads();
    for (int item = threadIdx.x; item < 32 * 64; item += 256) {
        int c = item >> 6, l = item & 63;
        int k  = c * 16 + (l & 15);
        int tl = (l >> 4) * 8;
        half8 h;
#pragma unroll
        for (int j = 0; j < 8; ++j) h[j] = (_Float16)w2[tl + j][k];
        *(half8*)&Af[(((size_t)ts * 32 + c) * 64 + l) * 8] = h;
    }
}

// ---------------- K1: g[b][k] = hc@We1 + be1 + be2 ----------------
__global__ __launch_bounds__(256) void k_hs(const float* __restrict__ hidden,
                                            const float* __restrict__ cell,
                                            const float* __restrict__ We1,
                                            const float* __restrict__ be1,
                                            const float* __restrict__ be2,
                                            float* __restrict__ g) {
    __shared__ __align__(16) float hcl[8][512];
    __shared__ float red[4][8][64];
    const int b0 = (blockIdx.x >> 3) << 3;
    const int k0 = (blockIdx.x & 7) << 6;
    for (int idx = threadIdx.x; idx < 8 * 512; idx += 256) {
        int bi = idx >> 9, j = idx & 511;
        hcl[bi][j] = (j < 256) ? hidden[(b0 + bi) * 256 + j]
                               : cell[(b0 + bi) * 256 + j - 256];
    }
    __syncthreads();
    const int kl = threadIdx.x & 63;
    const int jc = threadIdx.x >> 6;
    const int k  = k0 + kl;
    float acc[8] = {};
    for (int j = jc * 128; j < jc * 128 + 128; j += 4) {
        float w0 = We1[(j + 0) * 512 + k];
        float w1 = We1[(j + 1) * 512 + k];
        float w2 = We1[(j + 2) * 512 + k];
        float w3 = We1[(j + 3) * 512 + k];
#pragma unroll
        for (int bi = 0; bi < 8; ++bi) {
            float4 h = *(const float4*)&hcl[bi][j];
            acc[bi] += h.x * w0 + h.y * w1 + h.z * w2 + h.w * w3;
        }
    }
#pragma unroll
    for (int bi = 0; bi < 8; ++bi) red[jc][bi][kl] = acc[bi];
    __syncthreads();
    for (int idx = threadIdx.x; idx < 512; idx += 256) {
        int bi = idx >> 6, kk = idx & 63;
        float s = red[0][bi][kk] + red[1][bi][kk] + red[2][bi][kk] + red[3][bi][kk];
        int kg = k0 + kk;
        g[(b0 + bi) * 512 + kg] = s + be1[kg] + be2[kg];
    }
}

// ---------------- K2: TLP fused GEMM, no LDS staging ----------------
// grid 2048 = 128b x 8nt(64n) x 2kblk(256k), XCD chunk-swizzle (kblk-siblings
// co-XCD).  256 thr = 4 waves; wave wv: k [kblk*256+wv*64,+64) x n 64
// -> acc 4x4 = 16 MFMA/step, 16 steps, fully unrolled, barrier-free.
// B-frag: 8 dword gathers from global X (identical addrs across the 4 waves
// -> L1 broadcast), cvt_pkrtz pack.  A-frag: 4 b128 from L2-hot Af.
__global__ __launch_bounds__(256, 3) void k_main(const float* __restrict__ X,
                                                 const _Float16* __restrict__ Af,
                                                 const float* __restrict__ g,
                                                 const float* __restrict__ vvec,
                                                 float* __restrict__ Ep) {
    __shared__ float ered[256];       // epilogue only (1 KB)
    const int tid  = threadIdx.x;
    const int lane = tid & 63;
    const int wv   = tid >> 6;        // 0..3
    const int l16  = lane & 15;
    const int lhi  = lane >> 4;       // 0..3
    const int logical = (blockIdx.x & 7) * 256 + (blockIdx.x >> 3);
    const int kblk = logical & 1;
    const int nt   = (logical >> 1) & 7;
    const int b    = logical >> 4;
    const int n0   = nt << 6;

    // per-lane B gather base: row t = s*32 + lhi*8 + j, col n = n0+nf*16+l16
    const float* Xb0 = X + (size_t)b * 262144 + (size_t)(lhi * 8) * 512 + n0 + l16;
    const _Float16* Ag = Af + (size_t)(kblk * 16 + wv * 4) * 512 + (size_t)lane * 8;

    floatx4 acc[4][4];
#pragma unroll
    for (int a = 0; a < 4; ++a)
#pragma unroll
        for (int c = 0; c < 4; ++c) acc[a][c] = (floatx4){0.f, 0.f, 0.f, 0.f};

#pragma unroll
    for (int s = 0; s < 16; ++s) {
        // A(s): 4 coalesced b128 from L2-hot Af
        half8 af[4];
#pragma unroll
        for (int kf = 0; kf < 4; ++kf)
            af[kf] = *(const half8*)(Ag + (size_t)s * 16384 + (size_t)kf * 512);
        // B(s): 4 nf x 8 dword gathers + pack (L1-served, shared by 4 waves)
        half8 bf[4];
#pragma unroll
        for (int nf = 0; nf < 4; ++nf) {
            float f[8];
#pragma unroll
            for (int j = 0; j < 8; ++j)
                f[j] = Xb0[(size_t)(s * 32 + j) * 512 + nf * 16];
            union { half2v h2[4]; half8 h8; } u;
#pragma unroll
            for (int m = 0; m < 4; ++m)
                u.h2[m] = __builtin_bit_cast(half2v,
                              __builtin_amdgcn_cvt_pkrtz(f[2 * m], f[2 * m + 1]));
            bf[nf] = u.h8;
        }
        // 16 MFMA
#pragma unroll
        for (int kf = 0; kf < 4; ++kf)
#pragma unroll
            for (int nf = 0; nf < 4; ++nf)
                acc[kf][nf] = __builtin_amdgcn_mfma_f32_16x16x32_f16(
                    af[kf], bf[nf], acc[kf][nf], 0, 0, 0);
    }

    // ---- fused epilogue: s[n] = sum_{k in wave 64-slice} tanh(acc+g)*v
    // D layout: row k = lhi*4+reg (within kf 16-group), col n = l16
    const float* gb = g + b * 512;
    float sacc[4] = {0.f, 0.f, 0.f, 0.f};
#pragma unroll
    for (int kf = 0; kf < 4; ++kf) {
        const int kb = kblk * 256 + wv * 64 + kf * 16 + lhi * 4;
        float g0 = gb[kb + 0], g1 = gb[kb + 1], g2 = gb[kb + 2], g3 = gb[kb + 3];
        float v0 = vvec[kb + 0], v1 = vvec[kb + 1], v2 = vvec[kb + 2], v3 = vvec[kb + 3];
#pragma unroll
        for (int nf = 0; nf < 4; ++nf) {
            sacc[nf] += fast_tanh(acc[kf][nf][0] + g0) * v0;
            sacc[nf] += fast_tanh(acc[kf][nf][1] + g1) * v1;
            sacc[nf] += fast_tanh(acc[kf][nf][2] + g2) * v2;
            sacc[nf] += fast_tanh(acc[kf][nf][3] + g3) * v3;
        }
    }
#pragma unroll
    for (int nf = 0; nf < 4; ++nf) {
        sacc[nf] += __shfl_xor(sacc[nf], 16);
        sacc[nf] += __shfl_xor(sacc[nf], 32);
    }
    if (lane < 16) {
#pragma unroll
        for (int nf = 0; nf < 4; ++nf) ered[wv * 64 + nf * 16 + l16] = sacc[nf];
    }
    __syncthreads();
    if (tid < 64) {
        float e = ered[tid] + ered[64 + tid] + ered[128 + tid] + ered[192 + tid];
        Ep[(size_t)kblk * 65536 + b * 512 + n0 + tid] = e;
    }
}

// ---------------- K3: softmax over n (512), summing 2 k-partials ------------
__global__ __launch_bounds__(256) void k_softmax(const float* __restrict__ Ep,
                                                 float* __restrict__ out) {
    __shared__ float rmax[4], rsum[4];
    const int b = blockIdx.x;
    const int tid = threadIdx.x;
    const float* E0 = Ep;
    const float* E1 = Ep + 65536;
    float e0 = E0[b * 512 + tid] + E1[b * 512 + tid];
    float e1 = E0[b * 512 + 256 + tid] + E1[b * 512 + 256 + tid];
    float m = fmaxf(e0, e1);
    for (int o = 32; o > 0; o >>= 1) m = fmaxf(m, __shfl_xor(m, o));
    if ((tid & 63) == 0) rmax[tid >> 6] = m;
    __syncthreads();
    m = fmaxf(fmaxf(rmax[0], rmax[1]), fmaxf(rmax[2], rmax[3]));
    float p0 = __expf(e0 - m), p1 = __expf(e1 - m);
    float ss = p0 + p1;
    for (int o = 32; o > 0; o >>= 1) ss += __shfl_xor(ss, o);
    if ((tid & 63) == 0) rsum[tid >> 6] = ss;
    __syncthreads();
    ss = rsum[0] + rsum[1] + rsum[2] + rsum[3];
    float inv = __fdividef(1.0f, ss);
    out[b * 512 + tid] = p0 * inv;
    out[b * 512 + 256 + tid] = p1 * inv;
}

extern "C" void kernel_launch(void* const* d_in, const int* in_sizes, int n_in,
                              void* d_out, int out_size, void* d_ws, size_t ws_size,
                              hipStream_t stream) {
    const float* hidden = (const float*)d_in[0];
    const float* cell   = (const float*)d_in[1];
    const float* X      = (const float*)d_in[2];
    const float* We1    = (const float*)d_in[3];
    const float* be1    = (const float*)d_in[4];
    const float* We2    = (const float*)d_in[5];
    const float* be2    = (const float*)d_in[6];
    const float* v      = (const float*)d_in[7];
    float* out = (float*)d_out;

    char* ws = (char*)d_ws;
    _Float16* Af = (_Float16*)ws;                        // 512*512*2   = 524288 B
    float* g     = (float*)(ws + 524288);                // 128*512*4   = 262144 B
    float* Ep    = (float*)(ws + 786432);                // 2*128*512*4 = 524288 B

    k_prep_a<<<16, 256, 0, stream>>>(We2, Af);
    k_hs<<<128, 256, 0, stream>>>(hidden, cell, We1, be1, be2, g);
    k_main<<<2048, 256, 0, stream>>>(X, Af, g, v, Ep);
    k_softmax<<<128, 256, 0, stream>>>(Ep, out);
}